// Round 9
// baseline (2070.322 us; speedup 1.0000x reference)
//
#include <hip/hip_runtime.h>

#define B_SZ 128
#define T_SZ 512
#define D_SZ 128
#define H_SZ 512

#define NG 8    // batch groups
#define GB 16   // batch rows per group
#define NS 4    // column slices
#define SN 128  // columns per slice
#define EXB (GB * SN)        // 2048 f16 per (g,slice)
#define RING_ULL 16384       // NG*NS*EXB/4 ull per ring slot

typedef _Float16 f16;
typedef _Float16 f16x8 __attribute__((ext_vector_type(8)));
typedef _Float16 f16x4 __attribute__((ext_vector_type(4)));
typedef float f32x4 __attribute__((ext_vector_type(4)));
typedef unsigned long long ull;
typedef unsigned long long ull2 __attribute__((ext_vector_type(2)));
typedef unsigned int uint;

// ---------------- W_in transpose ----------------
__global__ __launch_bounds__(256) void transpose_k(const float* __restrict__ in,
                                                   float* __restrict__ out,
                                                   int R, int C) {
  __shared__ float tile[32][33];
  int c0 = blockIdx.x * 32, r0 = blockIdx.y * 32;
  int tx = threadIdx.x & 31, ty = threadIdx.x >> 5;
  for (int i = ty; i < 32; i += 8)
    tile[i][tx] = in[(size_t)(r0 + i) * C + (c0 + tx)];
  __syncthreads();
  for (int i = ty; i < 32; i += 8)
    out[(size_t)(c0 + i) * R + (r0 + tx)] = tile[tx][i];
}

// ---------------- x_in = x @ W_in^T + b ----------------
__global__ __launch_bounds__(256) void input_proj_k(
    const float* __restrict__ x,     // [BT][128]
    const float* __restrict__ WTin,  // [128][512]
    const float* __restrict__ bias,  // [512]
    float* __restrict__ out)         // [BT][512]
{
  __shared__ float xs[32 * 128];
  const int tid = threadIdx.x;
  const size_t r0 = (size_t)blockIdx.x * 32;

  const float4* xg = (const float4*)(x + r0 * D_SZ);
  float4* xs4s = (float4*)xs;
#pragma unroll
  for (int i = 0; i < 4; ++i) xs4s[tid + i * 256] = xg[tid + i * 256];
  __syncthreads();

  const int q = tid & 127;
  const int rg = tid >> 7;
  const float4* W4 = (const float4*)WTin;
  const float4* xs4 = (const float4*)xs;

  float acc[16][4];
#pragma unroll
  for (int r = 0; r < 16; ++r)
#pragma unroll
    for (int c = 0; c < 4; ++c) acc[r][c] = 0.f;

  for (int k4 = 0; k4 < 32; ++k4) {
    float w[4][4];
#pragma unroll
    for (int kk = 0; kk < 4; ++kk) {
      float4 wv = W4[(size_t)(k4 * 4 + kk) * 128 + q];
      w[kk][0] = wv.x; w[kk][1] = wv.y; w[kk][2] = wv.z; w[kk][3] = wv.w;
    }
#pragma unroll
    for (int r = 0; r < 16; ++r) {
      float4 xv = xs4[(rg * 16 + r) * 32 + k4];
      float xk[4] = {xv.x, xv.y, xv.z, xv.w};
#pragma unroll
      for (int kk = 0; kk < 4; ++kk)
#pragma unroll
        for (int c = 0; c < 4; ++c)
          acc[r][c] = fmaf(xk[kk], w[kk][c], acc[r][c]);
    }
  }

  float4 bv = ((const float4*)bias)[q];
  float bb[4] = {bv.x, bv.y, bv.z, bv.w};
#pragma unroll
  for (int r = 0; r < 16; ++r) {
    float4 o;
    o.x = acc[r][0] + bb[0];
    o.y = acc[r][1] + bb[1];
    o.z = acc[r][2] + bb[2];
    o.w = acc[r][3] + bb[3];
    ((float4*)(out + (r0 + rg * 16 + r) * H_SZ))[q] = o;
  }
}

__device__ __forceinline__ float fast_tanh(float y) {
  float e = __expf(2.0f * y);
  return 1.0f - __fdividef(2.0f, e + 1.0f);
}

__device__ __forceinline__ ull ld_agent(const ull* p) {
  return __hip_atomic_load(p, __ATOMIC_RELAXED, __HIP_MEMORY_SCOPE_AGENT);
}

// ---------------- recurrence ----------------
// 16 blocks x 512 threads. Waves 0-3 = group 2p, waves 4-7 = group 2p+1
// (p = blockIdx&3, slice = blockIdx>>2). Each wave owns TWO 16-col j-tiles
// (afrag 128 VGPR, B-frags shared). Exchange: self-tagged 8B words, depth-2
// LLC ring (relaxed sc1). Gathers for step s+1 are ISSUED right after the
// step-s publish (a full tail+verify away from use) -> first-try tag hits.
// ONE barrier per iter: peer-writes(s+1) land in hs[cur_{s+1}]=hs[nxt_s]
// (disjoint from own cols written at s); B1(s+1) orders all writes before
// MFMA(s+1) reads; MFMA(s) reads hs[cur_s] untouched until after B1(s+1).
__global__ __launch_bounds__(512, 2) void ltc_rec_mfma(
    float* __restrict__ seq,        // [B][T][H]  in: x_in, out: h_seq
    float* __restrict__ h_last,     // [B][H]
    const float* __restrict__ hin,  // [B][H]
    const float* __restrict__ tau,  // [B]
    const float* __restrict__ Wrec, // [H][H] row-major
    ull* __restrict__ exu)          // [2][NG][NS][GB][SN] f16 ring, as ull
{
  __shared__ __attribute__((aligned(16))) f16 hs[2][2][GB * H_SZ];  // [half][buf] 4x16KB

  const int tid = threadIdx.x;
  const int w = tid >> 6;          // wave 0..7
  const int half = w >> 2;         // group half 0/1
  const int wv = w & 3;            // wave-in-half
  const int l = tid & 63;
  const int m = l & 15;            // batch-in-group (MFMA col)
  const int kg = l >> 4;           // 0..3
  const int pairid = blockIdx.x & 3;
  const int slice = blockIdx.x >> 2;
  const int g = pairid * 2 + half;
  const int jt0 = slice * SN + wv * 32;  // tile0 base; tile1 = jt0+16
  const int b = g * GB + m;
  const int msk = (m & 7) << 3;

  // one-time: A-fragments for 2 j-tiles (literal indices -> registers)
  f16x8 af0[16], af1[16];
  {
    const float* wr0 = Wrec + (size_t)(jt0 + m) * H_SZ;
    const float* wr1 = wr0 + 16 * H_SZ;
#pragma unroll
    for (int ff = 0; ff < 16; ++ff) {
      const int k0 = ff * 32 + kg * 8;
      float4 u0 = *(const float4*)(wr0 + k0);
      float4 u1 = *(const float4*)(wr0 + k0 + 4);
      f16x8 a;
      a[0] = (f16)u0.x; a[1] = (f16)u0.y; a[2] = (f16)u0.z; a[3] = (f16)u0.w;
      a[4] = (f16)u1.x; a[5] = (f16)u1.y; a[6] = (f16)u1.z; a[7] = (f16)u1.w;
      af0[ff] = a;
      float4 v0 = *(const float4*)(wr1 + k0);
      float4 v1 = *(const float4*)(wr1 + k0 + 4);
      f16x8 c;
      c[0] = (f16)v0.x; c[1] = (f16)v0.y; c[2] = (f16)v0.z; c[3] = (f16)v0.w;
      c[4] = (f16)v1.x; c[5] = (f16)v1.y; c[6] = (f16)v1.z; c[7] = (f16)v1.w;
      af1[ff] = c;
    }
  }

  float hreg[2][4];
#pragma unroll
  for (int t = 0; t < 2; ++t) {
    float4 h0 = *(const float4*)(hin + (size_t)b * H_SZ + jt0 + t * 16 + kg * 4);
    hreg[t][0] = h0.x; hreg[t][1] = h0.y; hreg[t][2] = h0.z; hreg[t][3] = h0.w;
  }
  const float itau = 1.0f / tau[b];

  // init: own group's full h_0 into hs[half][0] (256 threads per half)
  {
    const int t8 = tid & 255;
    const int r = t8 >> 4;           // 0..15
    const int c0 = (t8 & 15) * 4;    // 0..60
#pragma unroll
    for (int q = 0; q < 8; ++q) {
      const int col = q * 64 + c0;
      float4 v = *(const float4*)(hin + (size_t)(g * GB + r) * H_SZ + col);
      const int e = (r * H_SZ + col) ^ ((r & 7) << 3);
      f16x4 hf;
      hf[0] = (f16)v.x; hf[1] = (f16)v.y; hf[2] = (f16)v.z; hf[3] = (f16)v.w;
      *(f16x4*)&hs[half][0][e] = hf;
    }
  }
  __syncthreads();

  // exchange indices (ull units, 32-bit offsets from SGPR base)
  const uint pidx = (uint)(((g * NS + slice) * EXB + m * SN + wv * 32 + kg * 4) >> 2);
  const int t8 = tid & 255;
  const int grow = t8 >> 4;          // 0..15
  const int gcol = (t8 & 15) * 8;    // 0..120
  uint gidx[3];
  int ge[3];
#pragma unroll
  for (int i = 0; i < 3; ++i) {
    const int ps = (slice + 1 + i) & 3;
    gidx[i] = (uint)(((g * NS + ps) * EXB + grow * SN + gcol) >> 2);
    ge[i] = (grow * H_SZ + ps * SN + gcol) ^ ((grow & 7) << 3);
  }

  // LDS addresses (literal ff -> hoisted loop-invariant regs)
  const int eown0 = (m * H_SZ + jt0 + kg * 4) ^ msk;
  const int eown1 = (m * H_SZ + jt0 + 16 + kg * 4) ^ msk;

  float* seqp = seq + (size_t)b * T_SZ * H_SZ + jt0 + kg * 4;
  float4 xin0 = *(const float4*)seqp;
  float4 xin1 = *(const float4*)(seqp + 16);

  ull gw[6];
#pragma unroll
  for (int i = 0; i < 6; ++i) gw[i] = 0;

  for (int s = 0; s < T_SZ; ++s) {
    const int cur = s & 1, nxt = cur ^ 1;

    if (s > 0) {
      // ---- verify pre-issued gathers (h_s peers), reload if stale ----
      const ull vtag = (ull)(((s - 1) >> 1) & 1);
      const uint voff = ((s - 1) & 1) ? (uint)RING_ULL : 0u;
#pragma unroll
      for (int i = 0; i < 3; ++i) {
        while ((gw[2 * i] & 1ULL) != vtag)     gw[2 * i]     = ld_agent(exu + voff + gidx[i]);
        while ((gw[2 * i + 1] & 1ULL) != vtag) gw[2 * i + 1] = ld_agent(exu + voff + gidx[i] + 1);
      }
      // ---- peer cols of h_s into hs[half][cur] (16B stores) ----
#pragma unroll
      for (int i = 0; i < 3; ++i) {
        ull2 t;
        t[0] = gw[2 * i];
        t[1] = gw[2 * i + 1];
        *(ull2*)&hs[half][cur][ge[i]] = t;
      }
    }
    __syncthreads();  // B1: hs[half][cur] complete (peer cols s>0, own cols from s-1)

    // ---- GEMM: 2 j-tiles, shared B-frags, K=512 ----
    f32x4 acc0 = {0.f, 0.f, 0.f, 0.f};
    f32x4 acc1 = {0.f, 0.f, 0.f, 0.f};
#pragma unroll
    for (int ff = 0; ff < 16; ++ff) {
      const int e = (m * H_SZ + ff * 32 + kg * 8) ^ msk;
      f16x8 bf = *(const f16x8*)&hs[half][cur][e];
      acc0 = __builtin_amdgcn_mfma_f32_16x16x32_f16(af0[ff], bf, acc0, 0, 0, 0);
      acc1 = __builtin_amdgcn_mfma_f32_16x16x32_f16(af1[ff], bf, acc1, 0, 0, 0);
    }

    // ---- epilogue (both tiles) ----
    float4 hv0, hv1;
    hv0.x = fmaf(fast_tanh(xin0.x + acc0[0]) - hreg[0][0], itau, hreg[0][0]);
    hv0.y = fmaf(fast_tanh(xin0.y + acc0[1]) - hreg[0][1], itau, hreg[0][1]);
    hv0.z = fmaf(fast_tanh(xin0.z + acc0[2]) - hreg[0][2], itau, hreg[0][2]);
    hv0.w = fmaf(fast_tanh(xin0.w + acc0[3]) - hreg[0][3], itau, hreg[0][3]);
    hv1.x = fmaf(fast_tanh(xin1.x + acc1[0]) - hreg[1][0], itau, hreg[1][0]);
    hv1.y = fmaf(fast_tanh(xin1.y + acc1[1]) - hreg[1][1], itau, hreg[1][1]);
    hv1.z = fmaf(fast_tanh(xin1.z + acc1[2]) - hreg[1][2], itau, hreg[1][2]);
    hv1.w = fmaf(fast_tanh(xin1.w + acc1[3]) - hreg[1][3], itau, hreg[1][3]);
    hreg[0][0] = hv0.x; hreg[0][1] = hv0.y; hreg[0][2] = hv0.z; hreg[0][3] = hv0.w;
    hreg[1][0] = hv1.x; hreg[1][1] = hv1.y; hreg[1][2] = hv1.z; hreg[1][3] = hv1.w;

    f16x4 hf0, hf1;
    hf0[0] = (f16)hv0.x; hf0[1] = (f16)hv0.y; hf0[2] = (f16)hv0.z; hf0[3] = (f16)hv0.w;
    hf1[0] = (f16)hv1.x; hf1[1] = (f16)hv1.y; hf1[2] = (f16)hv1.z; hf1[3] = (f16)hv1.w;

    // ---- publish h_{s+1}: slot s&1, tag (s>>1)&1, relaxed sc1 ----
    {
      const ull ptag = (ull)((s >> 1) & 1);
      const uint ioff = cur ? (uint)RING_ULL : 0u;
      ull b0 = (__builtin_bit_cast(ull, hf0) & ~1ULL) | ptag;
      ull b1 = (__builtin_bit_cast(ull, hf1) & ~1ULL) | ptag;
      __hip_atomic_store(exu + ioff + pidx, b0, __ATOMIC_RELAXED, __HIP_MEMORY_SCOPE_AGENT);
      __hip_atomic_store(exu + ioff + pidx + 4, b1, __ATOMIC_RELAXED, __HIP_MEMORY_SCOPE_AGENT);
    }

    // ---- local tail (covers peers' publish landing at LLC) ----
    *(f16x4*)&hs[half][nxt][eown0] = hf0;   // own cols of h_{s+1}
    *(f16x4*)&hs[half][nxt][eown1] = hf1;
    *(float4*)seqp = hv0;                   // h_seq output (plain cached)
    *(float4*)(seqp + 16) = hv1;
    seqp += H_SZ;
    xin0 = *(const float4*)seqp;            // x_in prefetch for s+1
    xin1 = *(const float4*)(seqp + 16);

    // ---- issue gathers for h_{s+1} (slot s&1); verified next iter ----
    {
      const uint ioff = cur ? (uint)RING_ULL : 0u;
#pragma unroll
      for (int i = 0; i < 3; ++i) {
        gw[2 * i]     = ld_agent(exu + ioff + gidx[i]);
        gw[2 * i + 1] = ld_agent(exu + ioff + gidx[i] + 1);
      }
    }
  }

  float4 hv;
  hv.x = hreg[0][0]; hv.y = hreg[0][1]; hv.z = hreg[0][2]; hv.w = hreg[0][3];
  *(float4*)(h_last + (size_t)b * H_SZ + jt0 + kg * 4) = hv;
  hv.x = hreg[1][0]; hv.y = hreg[1][1]; hv.z = hreg[1][2]; hv.w = hreg[1][3];
  *(float4*)(h_last + (size_t)b * H_SZ + jt0 + 16 + kg * 4) = hv;
}

extern "C" void kernel_launch(void* const* d_in, const int* in_sizes, int n_in,
                              void* d_out, int out_size, void* d_ws, size_t ws_size,
                              hipStream_t stream) {
  const float* x     = (const float*)d_in[0];
  const float* hin   = (const float*)d_in[1];
  const float* tau   = (const float*)d_in[2];
  const float* Win_w = (const float*)d_in[3];
  const float* Win_b = (const float*)d_in[4];
  const float* Wrec  = (const float*)d_in[5];

  float* out    = (float*)d_out;
  float* seq    = out;
  float* h_last = out + (size_t)B_SZ * T_SZ * H_SZ;

  ull*   ex   = (ull*)d_ws;                           // 256 KB (2-slot ring)
  float* WTin = (float*)((char*)d_ws + 262144);       // 256 KB

  // ring to 0xFF: LSB=1 never matches the first (tag-0) poll of each slot.
  hipMemsetAsync(ex, 0xFF, 2 * NG * NS * GB * SN * sizeof(f16), stream);

  dim3 blk(256);
  transpose_k<<<dim3(D_SZ / 32, H_SZ / 32), blk, 0, stream>>>(Win_w, WTin, H_SZ, D_SZ);
  input_proj_k<<<(B_SZ * T_SZ) / 32, blk, 0, stream>>>(x, WTin, Win_b, seq);
  ltc_rec_mfma<<<16, 512, 0, stream>>>(seq, h_last, hin, tau, Wrec, ex);
}

// Round 10
// 1597.063 us; speedup vs baseline: 1.2963x; 1.2963x over previous
//
#include <hip/hip_runtime.h>

#define B_SZ 128
#define T_SZ 512
#define D_SZ 128
#define H_SZ 512

#define NG 8    // batch groups
#define GB 16   // batch rows per group
#define NS 4    // column slices
#define SN 128  // columns per slice
#define EXB (GB * SN)        // 2048 f16 per (g,slice)
#define RING_ULL 16384       // NG*NS*EXB/4 ull per ring slot

typedef _Float16 f16;
typedef _Float16 f16x8 __attribute__((ext_vector_type(8)));
typedef _Float16 f16x4 __attribute__((ext_vector_type(4)));
typedef float f32x4 __attribute__((ext_vector_type(4)));
typedef unsigned long long ull;
typedef unsigned long long ull2 __attribute__((ext_vector_type(2)));
typedef unsigned int uint;

// lgkmcnt-only barrier: LDS ordering without draining global stores
// (publish/seq stores stay in flight across it; tag protocol needs no drain).
#define BAR()                                              \
  do {                                                     \
    asm volatile("s_waitcnt lgkmcnt(0)" ::: "memory");     \
    __builtin_amdgcn_sched_barrier(0);                     \
    __builtin_amdgcn_s_barrier();                          \
    __builtin_amdgcn_sched_barrier(0);                     \
  } while (0)

// ---------------- x_in = x @ W_in^T + b  (f16 MFMA, W in registers) --------
// 512 blocks x 256 thr (4 waves). Wave w owns cols [w*128, w*128+128).
// Block processes 8 row-tiles of 16 rows. A = W_in rows (f16), B = x rows.
__global__ __launch_bounds__(256) void input_proj_mfma(
    const float* __restrict__ x,     // [BT][128]
    const float* __restrict__ Win,   // [512][128] row-major
    const float* __restrict__ bias,  // [512]
    float* __restrict__ out)         // [BT][512]
{
  const int tid = threadIdx.x;
  const int w = tid >> 6;
  const int l = tid & 63;
  const int m = l & 15;
  const int kg = l >> 4;
  const int ht = w * 128;

  // W-frags: af[t][kb] = Win[ht + t*16 + m][kb*32 + kg*8 .. +8]  (128 VGPR)
  f16x8 af[8][4];
#pragma unroll
  for (int t = 0; t < 8; ++t) {
    const float* wr = Win + (size_t)(ht + t * 16 + m) * D_SZ;
#pragma unroll
    for (int kb = 0; kb < 4; ++kb) {
      const int k0 = kb * 32 + kg * 8;
      float4 u0 = *(const float4*)(wr + k0);
      float4 u1 = *(const float4*)(wr + k0 + 4);
      f16x8 a;
      a[0] = (f16)u0.x; a[1] = (f16)u0.y; a[2] = (f16)u0.z; a[3] = (f16)u0.w;
      a[4] = (f16)u1.x; a[5] = (f16)u1.y; a[6] = (f16)u1.z; a[7] = (f16)u1.w;
      af[t][kb] = a;
    }
  }

  for (int rt = 0; rt < 8; ++rt) {
    const size_t r0 = ((size_t)blockIdx.x * 8 + rt) * 16;
    const float* xr = x + (r0 + m) * D_SZ + kg * 8;
    f16x8 bf[4];
#pragma unroll
    for (int kb = 0; kb < 4; ++kb) {
      float4 u0 = *(const float4*)(xr + kb * 32);
      float4 u1 = *(const float4*)(xr + kb * 32 + 4);
      f16x8 a;
      a[0] = (f16)u0.x; a[1] = (f16)u0.y; a[2] = (f16)u0.z; a[3] = (f16)u0.w;
      a[4] = (f16)u1.x; a[5] = (f16)u1.y; a[6] = (f16)u1.z; a[7] = (f16)u1.w;
      bf[kb] = a;
    }
    f32x4 acc[8];
#pragma unroll
    for (int t = 0; t < 8; ++t) acc[t] = (f32x4){0.f, 0.f, 0.f, 0.f};
#pragma unroll
    for (int kb = 0; kb < 4; ++kb)
#pragma unroll
      for (int t = 0; t < 8; ++t)
        acc[t] = __builtin_amdgcn_mfma_f32_16x16x32_f16(af[t][kb], bf[kb], acc[t], 0, 0, 0);
#pragma unroll
    for (int t = 0; t < 8; ++t) {
      const int c0 = ht + t * 16 + kg * 4;
      float4 bb = *(const float4*)(bias + c0);
      float4 o;
      o.x = acc[t][0] + bb.x;
      o.y = acc[t][1] + bb.y;
      o.z = acc[t][2] + bb.z;
      o.w = acc[t][3] + bb.w;
      *(float4*)(out + (r0 + m) * H_SZ + c0) = o;
    }
  }
}

__device__ __forceinline__ float fast_tanh(float y) {
  float e = __expf(2.0f * y);
  return 1.0f - __fdividef(2.0f, e + 1.0f);
}

__device__ __forceinline__ ull ld_agent(const ull* p) {
  return __hip_atomic_load(p, __ATOMIC_RELAXED, __HIP_MEMORY_SCOPE_AGENT);
}

// ---------------- recurrence ----------------
// Round-8 base (8 waves x 1 j-tile, VGPR ~90) + (a) lgkm-only barriers
// (publish never drained — tag protocol doesn't need it; same-address store
// order is coherence-guaranteed so slot reuse at s+2 stays ordered),
// (b) 16B peer-col LDS writes via 768 gather units (waves 0-3: units tid and
// 512+tid; waves 4-7: unit tid — wave-uniform split, conflict-free groups).
__global__ __launch_bounds__(512) void ltc_rec_mfma(
    float* __restrict__ seq,        // [B][T][H]  in: x_in, out: h_seq
    float* __restrict__ h_last,     // [B][H]
    const float* __restrict__ hin,  // [B][H]
    const float* __restrict__ tau,  // [B]
    const float* __restrict__ Wrec, // [H][H] row-major
    ull* __restrict__ exu)          // [2][NG][NS][GB][SN] f16 ring, as ull
{
  __shared__ __attribute__((aligned(16))) f16 hs[2][GB * H_SZ];  // 2x16KB

  const int tid = threadIdx.x;
  const int g = blockIdx.x & 7;
  const int slice = blockIdx.x >> 3;
  const int w = tid >> 6;
  const int l = tid & 63;
  const int m = l & 15;
  const int kg = l >> 4;
  const int jt = slice * SN + w * 16;
  const int j0 = jt + kg * 4;
  const int b = g * GB + m;
  const int msk = (m & 7) << 3;

  // A-fragments, pre-rotated: afrag[0..3] = own-slice K, [4..15] = peer K.
  f16x8 afrag[16];
  {
    const float* wr = Wrec + (size_t)(jt + m) * H_SZ;
#pragma unroll
    for (int ff = 0; ff < 16; ++ff) {
      const int f = (slice * 4 + ff) & 15;
      const int k0 = f * 32 + kg * 8;
      float4 u0 = *(const float4*)(wr + k0);
      float4 u1 = *(const float4*)(wr + k0 + 4);
      f16x8 a;
      a[0] = (f16)u0.x; a[1] = (f16)u0.y; a[2] = (f16)u0.z; a[3] = (f16)u0.w;
      a[4] = (f16)u1.x; a[5] = (f16)u1.y; a[6] = (f16)u1.z; a[7] = (f16)u1.w;
      afrag[ff] = a;
    }
  }

  float hreg[4];
  {
    float4 h0 = *(const float4*)(hin + (size_t)b * H_SZ + j0);
    hreg[0] = h0.x; hreg[1] = h0.y; hreg[2] = h0.z; hreg[3] = h0.w;
  }
  const float itau = 1.0f / tau[b];

  // init: full h_0 into hs[0]
  {
    const int mr = tid >> 5;
    const int c4 = (tid & 31) * 4;
#pragma unroll
    for (int p = 0; p < 4; ++p) {
      const int col = p * SN + c4;
      float4 v = *(const float4*)(hin + (size_t)(g * GB + mr) * H_SZ + col);
      const int e = (mr * H_SZ + col) ^ ((mr & 7) << 3);
      f16x4 hf;
      hf[0] = (f16)v.x; hf[1] = (f16)v.y; hf[2] = (f16)v.z; hf[3] = (f16)v.w;
      *(f16x4*)&hs[0][e] = hf;
    }
  }
  __syncthreads();  // prologue only

  // publish index (ull units)
  const uint pidx = (uint)((g * 4 + slice) * 512 + m * 32 + w * 4 + kg);

  // gather units: uA = tid (peers 0,1), uB = 512+tid for tid<256 (peer 2)
  const int qA = tid & 255, pnoA = tid >> 8;
  const int psA = (slice + 1 + pnoA) & 3;
  const int rowA = qA >> 4, cA = qA & 15;
  const uint gA = (uint)((g * 4 + psA) * 512 + rowA * 32 + cA * 2);
  const int eA = (rowA * H_SZ + psA * SN + cA * 8) ^ ((rowA & 7) << 3);

  const int psB = (slice + 3) & 3;
  const int rowB = qA >> 4, cB = qA & 15;  // valid when tid<256
  const uint gB = (uint)((g * 4 + psB) * 512 + rowB * 32 + cB * 2);
  const int eB = (rowB * H_SZ + psB * SN + cB * 8) ^ ((rowB & 7) << 3);

  // LDS byte offsets for the 16 k-block reads (literal ff indices)
  int ebase[16];
#pragma unroll
  for (int ff = 0; ff < 16; ++ff) {
    const int f = (slice * 4 + ff) & 15;
    ebase[ff] = (m * H_SZ + f * 32 + kg * 8) ^ msk;
  }
  const int eown = (m * H_SZ + j0) ^ msk;

  float* seqp = seq + (size_t)b * T_SZ * H_SZ + j0;
  float4 xin = *(const float4*)seqp;

  ull gwA0 = 0, gwA1 = 0, gwB0 = 0, gwB1 = 0;

  for (int s = 0; s < T_SZ; ++s) {
    const int cur = s & 1, nxt = cur ^ 1;

    // ---- own-K MFMA (afrag[0..3]; own cols written before prev B2) ----
    f32x4 accA = {0.f, 0.f, 0.f, 0.f};
    accA = __builtin_amdgcn_mfma_f32_16x16x32_f16(afrag[0], *(const f16x8*)&hs[cur][ebase[0]], accA, 0, 0, 0);
    accA = __builtin_amdgcn_mfma_f32_16x16x32_f16(afrag[1], *(const f16x8*)&hs[cur][ebase[1]], accA, 0, 0, 0);
    accA = __builtin_amdgcn_mfma_f32_16x16x32_f16(afrag[2], *(const f16x8*)&hs[cur][ebase[2]], accA, 0, 0, 0);
    accA = __builtin_amdgcn_mfma_f32_16x16x32_f16(afrag[3], *(const f16x8*)&hs[cur][ebase[3]], accA, 0, 0, 0);

    if (s > 0) {
      // ---- verify pre-issued gathers; 16B LDS writes ----
      const ull vtag = (ull)(((s - 1) >> 1) & 1);
      const uint voff = ((s - 1) & 1) ? (uint)RING_ULL : 0u;
      while ((gwA0 & 1ULL) != vtag) gwA0 = ld_agent(exu + voff + gA);
      while ((gwA1 & 1ULL) != vtag) gwA1 = ld_agent(exu + voff + gA + 1);
      {
        ull2 t; t[0] = gwA0; t[1] = gwA1;
        *(ull2*)&hs[cur][eA] = t;
      }
      if (tid < 256) {  // waves 0-3 (wave-uniform)
        while ((gwB0 & 1ULL) != vtag) gwB0 = ld_agent(exu + voff + gB);
        while ((gwB1 & 1ULL) != vtag) gwB1 = ld_agent(exu + voff + gB + 1);
        ull2 t; t[0] = gwB0; t[1] = gwB1;
        *(ull2*)&hs[cur][eB] = t;
      }
    }
    BAR();  // B1: peer cols of h_s visible block-wide (no vm drain)

    // ---- peer-K MFMA (afrag[4..15], 2 chains) ----
    f32x4 accB = {0.f, 0.f, 0.f, 0.f};
    f32x4 accC = {0.f, 0.f, 0.f, 0.f};
    accB = __builtin_amdgcn_mfma_f32_16x16x32_f16(afrag[4],  *(const f16x8*)&hs[cur][ebase[4]],  accB, 0, 0, 0);
    accB = __builtin_amdgcn_mfma_f32_16x16x32_f16(afrag[5],  *(const f16x8*)&hs[cur][ebase[5]],  accB, 0, 0, 0);
    accB = __builtin_amdgcn_mfma_f32_16x16x32_f16(afrag[6],  *(const f16x8*)&hs[cur][ebase[6]],  accB, 0, 0, 0);
    accB = __builtin_amdgcn_mfma_f32_16x16x32_f16(afrag[7],  *(const f16x8*)&hs[cur][ebase[7]],  accB, 0, 0, 0);
    accB = __builtin_amdgcn_mfma_f32_16x16x32_f16(afrag[8],  *(const f16x8*)&hs[cur][ebase[8]],  accB, 0, 0, 0);
    accB = __builtin_amdgcn_mfma_f32_16x16x32_f16(afrag[9],  *(const f16x8*)&hs[cur][ebase[9]],  accB, 0, 0, 0);
    accC = __builtin_amdgcn_mfma_f32_16x16x32_f16(afrag[10], *(const f16x8*)&hs[cur][ebase[10]], accC, 0, 0, 0);
    accC = __builtin_amdgcn_mfma_f32_16x16x32_f16(afrag[11], *(const f16x8*)&hs[cur][ebase[11]], accC, 0, 0, 0);
    accC = __builtin_amdgcn_mfma_f32_16x16x32_f16(afrag[12], *(const f16x8*)&hs[cur][ebase[12]], accC, 0, 0, 0);
    accC = __builtin_amdgcn_mfma_f32_16x16x32_f16(afrag[13], *(const f16x8*)&hs[cur][ebase[13]], accC, 0, 0, 0);
    accC = __builtin_amdgcn_mfma_f32_16x16x32_f16(afrag[14], *(const f16x8*)&hs[cur][ebase[14]], accC, 0, 0, 0);
    accC = __builtin_amdgcn_mfma_f32_16x16x32_f16(afrag[15], *(const f16x8*)&hs[cur][ebase[15]], accC, 0, 0, 0);
    f32x4 acc = accA + accB + accC;

    // ---- epilogue ----
    float4 hv;
    hv.x = fmaf(fast_tanh(xin.x + acc[0]) - hreg[0], itau, hreg[0]);
    hv.y = fmaf(fast_tanh(xin.y + acc[1]) - hreg[1], itau, hreg[1]);
    hv.z = fmaf(fast_tanh(xin.z + acc[2]) - hreg[2], itau, hreg[2]);
    hv.w = fmaf(fast_tanh(xin.w + acc[3]) - hreg[3], itau, hreg[3]);
    hreg[0] = hv.x; hreg[1] = hv.y; hreg[2] = hv.z; hreg[3] = hv.w;

    f16x4 hf;
    hf[0] = (f16)hv.x; hf[1] = (f16)hv.y; hf[2] = (f16)hv.z; hf[3] = (f16)hv.w;

    // ---- publish h_{s+1}: slot s&1, tag (s>>1)&1 ----
    const uint ioff = cur ? (uint)RING_ULL : 0u;
    {
      ull bits = (__builtin_bit_cast(ull, hf) & ~1ULL) | (ull)((s >> 1) & 1);
      __hip_atomic_store(exu + ioff + pidx, bits, __ATOMIC_RELAXED, __HIP_MEMORY_SCOPE_AGENT);
    }

    // ---- issue gathers for h_{s+1} (same slot); verified next iter ----
    gwA0 = ld_agent(exu + ioff + gA);
    gwA1 = ld_agent(exu + ioff + gA + 1);
    if (tid < 256) {
      gwB0 = ld_agent(exu + ioff + gB);
      gwB1 = ld_agent(exu + ioff + gB + 1);
    }

    // ---- local tail ----
    *(f16x4*)&hs[nxt][eown] = hf;   // own cols of h_{s+1}
    *(float4*)seqp = hv;            // h_seq output (plain cached)
    seqp += H_SZ;
    xin = *(const float4*)seqp;     // x_in prefetch for s+1

    BAR();  // B2: own cols of hs[nxt] ready (no vm drain)
  }

  float4 hv;
  hv.x = hreg[0]; hv.y = hreg[1]; hv.z = hreg[2]; hv.w = hreg[3];
  *(float4*)(h_last + (size_t)b * H_SZ + j0) = hv;
}

extern "C" void kernel_launch(void* const* d_in, const int* in_sizes, int n_in,
                              void* d_out, int out_size, void* d_ws, size_t ws_size,
                              hipStream_t stream) {
  const float* x     = (const float*)d_in[0];
  const float* hin   = (const float*)d_in[1];
  const float* tau   = (const float*)d_in[2];
  const float* Win_w = (const float*)d_in[3];
  const float* Win_b = (const float*)d_in[4];
  const float* Wrec  = (const float*)d_in[5];

  float* out    = (float*)d_out;
  float* seq    = out;
  float* h_last = out + (size_t)B_SZ * T_SZ * H_SZ;

  ull* ex = (ull*)d_ws;  // 256 KB (2-slot ring)

  // ring to 0xFF: LSB=1 never matches the first (tag-0) poll of each slot.
  hipMemsetAsync(ex, 0xFF, 2 * NG * NS * GB * SN * sizeof(f16), stream);

  input_proj_mfma<<<512, 256, 0, stream>>>(x, Win_w, Win_b, seq);
  ltc_rec_mfma<<<NG * NS, 512, 0, stream>>>(seq, h_last, hin, tau, Wrec, ex);
}

// Round 11
// 1302.942 us; speedup vs baseline: 1.5890x; 1.2257x over previous
//
#include <hip/hip_runtime.h>

#define B_SZ 128
#define T_SZ 512
#define D_SZ 128
#define H_SZ 512

#define NG 8     // batch groups
#define GB 16    // batch rows per group
#define NSL 2    // column slices (blocks per group)
#define SNW 256  // columns per slice
#define RING_ULL 16384  // NG*NSL*GB*SNW/4 ull per ring slot (128 KB)

typedef _Float16 f16;
typedef _Float16 f16x8 __attribute__((ext_vector_type(8)));
typedef _Float16 f16x4 __attribute__((ext_vector_type(4)));
typedef float f32x4 __attribute__((ext_vector_type(4)));
typedef unsigned long long ull;
typedef unsigned long long ull2 __attribute__((ext_vector_type(2)));
typedef unsigned int uint;

// lgkm-only barrier: orders LDS without draining global stores.
#define BAR_LGKM()                                         \
  do {                                                     \
    asm volatile("s_waitcnt lgkmcnt(0)" ::: "memory");     \
    __builtin_amdgcn_s_barrier();                          \
  } while (0)

// ---------------- x_in = x @ W_in^T + b  (f16 MFMA, W in registers) --------
__global__ __launch_bounds__(256) void input_proj_mfma(
    const float* __restrict__ x,     // [BT][128]
    const float* __restrict__ Win,   // [512][128] row-major
    const float* __restrict__ bias,  // [512]
    float* __restrict__ out)         // [BT][512]
{
  const int tid = threadIdx.x;
  const int w = tid >> 6;
  const int l = tid & 63;
  const int m = l & 15;
  const int kg = l >> 4;
  const int ht = w * 128;

  f16x8 af[8][4];
#pragma unroll
  for (int t = 0; t < 8; ++t) {
    const float* wr = Win + (size_t)(ht + t * 16 + m) * D_SZ;
#pragma unroll
    for (int kb = 0; kb < 4; ++kb) {
      const int k0 = kb * 32 + kg * 8;
      float4 u0 = *(const float4*)(wr + k0);
      float4 u1 = *(const float4*)(wr + k0 + 4);
      f16x8 a;
      a[0] = (f16)u0.x; a[1] = (f16)u0.y; a[2] = (f16)u0.z; a[3] = (f16)u0.w;
      a[4] = (f16)u1.x; a[5] = (f16)u1.y; a[6] = (f16)u1.z; a[7] = (f16)u1.w;
      af[t][kb] = a;
    }
  }

  for (int rt = 0; rt < 8; ++rt) {
    const size_t r0 = ((size_t)blockIdx.x * 8 + rt) * 16;
    const float* xr = x + (r0 + m) * D_SZ + kg * 8;
    f16x8 bf[4];
#pragma unroll
    for (int kb = 0; kb < 4; ++kb) {
      float4 u0 = *(const float4*)(xr + kb * 32);
      float4 u1 = *(const float4*)(xr + kb * 32 + 4);
      f16x8 a;
      a[0] = (f16)u0.x; a[1] = (f16)u0.y; a[2] = (f16)u0.z; a[3] = (f16)u0.w;
      a[4] = (f16)u1.x; a[5] = (f16)u1.y; a[6] = (f16)u1.z; a[7] = (f16)u1.w;
      bf[kb] = a;
    }
    f32x4 acc[8];
#pragma unroll
    for (int t = 0; t < 8; ++t) acc[t] = (f32x4){0.f, 0.f, 0.f, 0.f};
#pragma unroll
    for (int kb = 0; kb < 4; ++kb)
#pragma unroll
      for (int t = 0; t < 8; ++t)
        acc[t] = __builtin_amdgcn_mfma_f32_16x16x32_f16(af[t][kb], bf[kb], acc[t], 0, 0, 0);
#pragma unroll
    for (int t = 0; t < 8; ++t) {
      const int c0 = ht + t * 16 + kg * 4;
      float4 bb = *(const float4*)(bias + c0);
      float4 o;
      o.x = acc[t][0] + bb.x;
      o.y = acc[t][1] + bb.y;
      o.z = acc[t][2] + bb.z;
      o.w = acc[t][3] + bb.w;
      *(float4*)(out + (r0 + m) * H_SZ + c0) = o;
    }
  }
}

__device__ __forceinline__ float fast_tanh(float y) {
  float e = __expf(2.0f * y);
  return 1.0f - __fdividef(2.0f, e + 1.0f);
}

__device__ __forceinline__ ull ld_agent(const ull* p) {
  return __hip_atomic_load(p, __ATOMIC_RELAXED, __HIP_MEMORY_SCOPE_AGENT);
}

// ---------------- recurrence (NS=2) ----------------
// 16 blocks x 512 threads (8 waves x 2 j-tiles; af0+af1 = 128 VGPR, natural
// cap 256 at 512 thr — no second launch_bounds arg!). One peer block.
// Round-8 gather timing: issue at top of iter (after B2), own-K (8 k-blocks)
// covers flight, poll verifies, B1 = __syncthreads (vmcnt already drained by
// poll), peer-K (8 k-blocks), epilogue, tagged publish, own cols, B2 =
// lgkm-only (publish stays in flight; its drain lands in next poll, covered).
__global__ __launch_bounds__(512) void ltc_rec_mfma(
    float* __restrict__ seq,        // [B][T][H]  in: x_in, out: h_seq
    float* __restrict__ h_last,     // [B][H]
    const float* __restrict__ hin,  // [B][H]
    const float* __restrict__ tau,  // [B]
    const float* __restrict__ Wrec, // [H][H] row-major
    ull* __restrict__ exu)          // [2][NG][NSL][GB][SNW] f16 ring, as ull
{
  __shared__ __attribute__((aligned(16))) f16 hs[2][GB * H_SZ];  // 2x16KB

  const int tid = threadIdx.x;
  const int g = blockIdx.x >> 1;
  const int slice = blockIdx.x & 1;
  const int w = tid >> 6;
  const int l = tid & 63;
  const int m = l & 15;
  const int kg = l >> 4;
  const int jt0 = slice * SNW + w * 32;   // tile0 base (global col); tile1 = +16
  const int b = g * GB + m;
  const int msk = (m & 7) << 3;

  // A-fragments, 2 tiles, pre-rotated: ff -> k-block f=(slice*8+ff)&15.
  // ff 0..7 = own-slice K, ff 8..15 = peer K. Literal indices -> registers.
  f16x8 af0[16], af1[16];
  {
    const float* wr0 = Wrec + (size_t)(jt0 + m) * H_SZ;
    const float* wr1 = wr0 + 16 * H_SZ;
#pragma unroll
    for (int ff = 0; ff < 16; ++ff) {
      const int f = (slice * 8 + ff) & 15;
      const int k0 = f * 32 + kg * 8;
      float4 u0 = *(const float4*)(wr0 + k0);
      float4 u1 = *(const float4*)(wr0 + k0 + 4);
      f16x8 a;
      a[0] = (f16)u0.x; a[1] = (f16)u0.y; a[2] = (f16)u0.z; a[3] = (f16)u0.w;
      a[4] = (f16)u1.x; a[5] = (f16)u1.y; a[6] = (f16)u1.z; a[7] = (f16)u1.w;
      af0[ff] = a;
      float4 v0 = *(const float4*)(wr1 + k0);
      float4 v1 = *(const float4*)(wr1 + k0 + 4);
      f16x8 c;
      c[0] = (f16)v0.x; c[1] = (f16)v0.y; c[2] = (f16)v0.z; c[3] = (f16)v0.w;
      c[4] = (f16)v1.x; c[5] = (f16)v1.y; c[6] = (f16)v1.z; c[7] = (f16)v1.w;
      af1[ff] = c;
    }
  }

  float hreg[2][4];
#pragma unroll
  for (int t = 0; t < 2; ++t) {
    float4 h0 = *(const float4*)(hin + (size_t)b * H_SZ + jt0 + t * 16 + kg * 4);
    hreg[t][0] = h0.x; hreg[t][1] = h0.y; hreg[t][2] = h0.z; hreg[t][3] = h0.w;
  }
  const float itau = 1.0f / tau[b];

  // init: full h_0 into hs[0]
  {
    const int mr = tid >> 5;
    const int c4 = (tid & 31) * 4;
#pragma unroll
    for (int p = 0; p < 4; ++p) {
      const int col = p * 128 + c4;
      float4 v = *(const float4*)(hin + (size_t)(g * GB + mr) * H_SZ + col);
      const int e = (mr * H_SZ + col) ^ ((mr & 7) << 3);
      f16x4 hf;
      hf[0] = (f16)v.x; hf[1] = (f16)v.y; hf[2] = (f16)v.z; hf[3] = (f16)v.w;
      *(f16x4*)&hs[0][e] = hf;
    }
  }
  __syncthreads();

  // publish (ull units): ring[slot][g][slice][m][col]; colull = w*8+kg (tile0)
  const uint pidx0 = (uint)((g * NSL + slice) * 1024 + m * 64 + w * 8 + kg);
  const uint pidx1 = pidx0 + 4;  // tile1 (+16 f16)

  // gather: thread tid -> 2 consecutive ull of the peer slice buffer
  const int ps = slice ^ 1;
  const int grow = tid >> 5;                 // 0..15
  const int gcu = (tid & 31) * 2;            // ull-in-row 0..62
  const uint gidx = (uint)((g * NSL + ps) * 1024 + grow * 64 + gcu);
  const int eG = (grow * H_SZ + ps * SNW + (tid & 31) * 8) ^ ((grow & 7) << 3);

  // LDS byte offsets for the 16 k-block B-frag reads (literal ff)
  int ebase[16];
#pragma unroll
  for (int ff = 0; ff < 16; ++ff) {
    const int f = (slice * 8 + ff) & 15;
    ebase[ff] = (m * H_SZ + f * 32 + kg * 8) ^ msk;
  }
  const int eown0 = (m * H_SZ + jt0 + kg * 4) ^ msk;
  const int eown1 = (m * H_SZ + jt0 + 16 + kg * 4) ^ msk;

  float* seqp = seq + (size_t)b * T_SZ * H_SZ + jt0 + kg * 4;
  float4 xin0 = *(const float4*)seqp;
  float4 xin1 = *(const float4*)(seqp + 16);

  for (int s = 0; s < T_SZ; ++s) {
    const int cur = s & 1, nxt = cur ^ 1;

    // ---- issue gathers for h_s peer slice (published end of iter s-1) ----
    ull gw0 = 0, gw1 = 0;
    const uint voff = ((s - 1) & 1) ? (uint)RING_ULL : 0u;
    if (s > 0) {
      gw0 = ld_agent(exu + voff + gidx);
      gw1 = ld_agent(exu + voff + gidx + 1);
    }

    // ---- own-K MFMA (ff=0..7, both tiles): covers the gather flight ----
    f32x4 acc0 = {0.f, 0.f, 0.f, 0.f};
    f32x4 acc1 = {0.f, 0.f, 0.f, 0.f};
#pragma unroll
    for (int ff = 0; ff < 8; ++ff) {
      f16x8 bf = *(const f16x8*)&hs[cur][ebase[ff]];
      acc0 = __builtin_amdgcn_mfma_f32_16x16x32_f16(af0[ff], bf, acc0, 0, 0, 0);
      acc1 = __builtin_amdgcn_mfma_f32_16x16x32_f16(af1[ff], bf, acc1, 0, 0, 0);
    }

    if (s > 0) {
      // ---- poll tags; reload only stale words ----
      const ull vtag = (ull)(((s - 1) >> 1) & 1);
      while ((gw0 & 1ULL) != vtag) gw0 = ld_agent(exu + voff + gidx);
      while ((gw1 & 1ULL) != vtag) gw1 = ld_agent(exu + voff + gidx + 1);
      // ---- peer cols of h_s into hs[cur], 16B ----
      ull2 t; t[0] = gw0; t[1] = gw1;
      *(ull2*)&hs[cur][eG] = t;
      __syncthreads();  // B1 (vmcnt ~drained by poll already)
    }

    // ---- peer-K MFMA (ff=8..15, both tiles) ----
#pragma unroll
    for (int ff = 8; ff < 16; ++ff) {
      f16x8 bf = *(const f16x8*)&hs[cur][ebase[ff]];
      acc0 = __builtin_amdgcn_mfma_f32_16x16x32_f16(af0[ff], bf, acc0, 0, 0, 0);
      acc1 = __builtin_amdgcn_mfma_f32_16x16x32_f16(af1[ff], bf, acc1, 0, 0, 0);
    }

    // ---- epilogue (both tiles) ----
    float4 hv0, hv1;
    hv0.x = fmaf(fast_tanh(xin0.x + acc0[0]) - hreg[0][0], itau, hreg[0][0]);
    hv0.y = fmaf(fast_tanh(xin0.y + acc0[1]) - hreg[0][1], itau, hreg[0][1]);
    hv0.z = fmaf(fast_tanh(xin0.z + acc0[2]) - hreg[0][2], itau, hreg[0][2]);
    hv0.w = fmaf(fast_tanh(xin0.w + acc0[3]) - hreg[0][3], itau, hreg[0][3]);
    hv1.x = fmaf(fast_tanh(xin1.x + acc1[0]) - hreg[1][0], itau, hreg[1][0]);
    hv1.y = fmaf(fast_tanh(xin1.y + acc1[1]) - hreg[1][1], itau, hreg[1][1]);
    hv1.z = fmaf(fast_tanh(xin1.z + acc1[2]) - hreg[1][2], itau, hreg[1][2]);
    hv1.w = fmaf(fast_tanh(xin1.w + acc1[3]) - hreg[1][3], itau, hreg[1][3]);
    hreg[0][0] = hv0.x; hreg[0][1] = hv0.y; hreg[0][2] = hv0.z; hreg[0][3] = hv0.w;
    hreg[1][0] = hv1.x; hreg[1][1] = hv1.y; hreg[1][2] = hv1.z; hreg[1][3] = hv1.w;

    f16x4 hf0, hf1;
    hf0[0] = (f16)hv0.x; hf0[1] = (f16)hv0.y; hf0[2] = (f16)hv0.z; hf0[3] = (f16)hv0.w;
    hf1[0] = (f16)hv1.x; hf1[1] = (f16)hv1.y; hf1[2] = (f16)hv1.z; hf1[3] = (f16)hv1.w;

    // ---- publish h_{s+1}: slot s&1, tag (s>>1)&1 ----
    {
      const uint ioff = cur ? (uint)RING_ULL : 0u;
      const ull ptag = (ull)((s >> 1) & 1);
      ull b0 = (__builtin_bit_cast(ull, hf0) & ~1ULL) | ptag;
      ull b1 = (__builtin_bit_cast(ull, hf1) & ~1ULL) | ptag;
      __hip_atomic_store(exu + ioff + pidx0, b0, __ATOMIC_RELAXED, __HIP_MEMORY_SCOPE_AGENT);
      __hip_atomic_store(exu + ioff + pidx1, b1, __ATOMIC_RELAXED, __HIP_MEMORY_SCOPE_AGENT);
    }

    // ---- local tail ----
    *(f16x4*)&hs[nxt][eown0] = hf0;   // own cols of h_{s+1}
    *(f16x4*)&hs[nxt][eown1] = hf1;
    *(float4*)seqp = hv0;             // h_seq output (plain cached)
    *(float4*)(seqp + 16) = hv1;
    seqp += H_SZ;
    xin0 = *(const float4*)seqp;      // x_in prefetch for s+1
    xin1 = *(const float4*)(seqp + 16);

    BAR_LGKM();  // B2: LDS-only ordering; publish stays in flight
  }

  float4 hv;
  hv.x = hreg[0][0]; hv.y = hreg[0][1]; hv.z = hreg[0][2]; hv.w = hreg[0][3];
  *(float4*)(h_last + (size_t)b * H_SZ + jt0 + kg * 4) = hv;
  hv.x = hreg[1][0]; hv.y = hreg[1][1]; hv.z = hreg[1][2]; hv.w = hreg[1][3];
  *(float4*)(h_last + (size_t)b * H_SZ + jt0 + 16 + kg * 4) = hv;
}

extern "C" void kernel_launch(void* const* d_in, const int* in_sizes, int n_in,
                              void* d_out, int out_size, void* d_ws, size_t ws_size,
                              hipStream_t stream) {
  const float* x     = (const float*)d_in[0];
  const float* hin   = (const float*)d_in[1];
  const float* tau   = (const float*)d_in[2];
  const float* Win_w = (const float*)d_in[3];
  const float* Win_b = (const float*)d_in[4];
  const float* Wrec  = (const float*)d_in[5];

  float* out    = (float*)d_out;
  float* seq    = out;
  float* h_last = out + (size_t)B_SZ * T_SZ * H_SZ;

  ull* ex = (ull*)d_ws;  // 256 KB (2-slot ring)

  // ring to 0xFF: LSB=1 never matches the first (tag-0) poll of each slot.
  hipMemsetAsync(ex, 0xFF, 2 * NG * NSL * GB * SNW * sizeof(f16), stream);

  input_proj_mfma<<<512, 256, 0, stream>>>(x, Win_w, Win_b, seq);
  ltc_rec_mfma<<<NG * NSL, 512, 0, stream>>>(seq, h_last, hin, tau, Wrec, ex);
}

// Round 13
// 1058.484 us; speedup vs baseline: 1.9559x; 1.2310x over previous
//
#include <hip/hip_runtime.h>

#define B_SZ 128
#define T_SZ 512
#define D_SZ 128
#define H_SZ 512

#define NG 8    // batch groups
#define GB 16   // batch rows per group
#define NS 4    // column slices
#define SN 128  // columns per slice
#define RING_ULL 16384  // NG*NS*GB*SN/4 ull per ring slot (128 KB)

typedef _Float16 f16;
typedef _Float16 f16x8 __attribute__((ext_vector_type(8)));
typedef _Float16 f16x4 __attribute__((ext_vector_type(4)));
typedef float f32x4 __attribute__((ext_vector_type(4)));
typedef unsigned long long ull;
typedef unsigned int uint;

// lgkm-only barrier: orders LDS block-wide WITHOUT draining vmcnt.
// The publish store stays in flight across it; its completion is enforced
// by the next iteration's poll via in-order vmcnt, covered by own-K MFMA.
#define BAR_LGKM()                                         \
  do {                                                     \
    asm volatile("s_waitcnt lgkmcnt(0)" ::: "memory");     \
    __builtin_amdgcn_sched_barrier(0);                     \
    __builtin_amdgcn_s_barrier();                          \
    __builtin_amdgcn_sched_barrier(0);                     \
  } while (0)

// ---------------- x_in = x @ W_in^T + b  (f16 MFMA, W in registers) --------
// Validated round 10: non-rec time 113 -> 54 us, absmax unchanged.
__global__ __launch_bounds__(256) void input_proj_mfma(
    const float* __restrict__ x,     // [BT][128]
    const float* __restrict__ Win,   // [512][128] row-major
    const float* __restrict__ bias,  // [512]
    float* __restrict__ out)         // [BT][512]
{
  const int tid = threadIdx.x;
  const int w = tid >> 6;
  const int l = tid & 63;
  const int m = l & 15;
  const int kg = l >> 4;
  const int ht = w * 128;

  f16x8 af[8][4];
#pragma unroll
  for (int t = 0; t < 8; ++t) {
    const float* wr = Win + (size_t)(ht + t * 16 + m) * D_SZ;
#pragma unroll
    for (int kb = 0; kb < 4; ++kb) {
      const int k0 = kb * 32 + kg * 8;
      float4 u0 = *(const float4*)(wr + k0);
      float4 u1 = *(const float4*)(wr + k0 + 4);
      f16x8 a;
      a[0] = (f16)u0.x; a[1] = (f16)u0.y; a[2] = (f16)u0.z; a[3] = (f16)u0.w;
      a[4] = (f16)u1.x; a[5] = (f16)u1.y; a[6] = (f16)u1.z; a[7] = (f16)u1.w;
      af[t][kb] = a;
    }
  }

  for (int rt = 0; rt < 8; ++rt) {
    const size_t r0 = ((size_t)blockIdx.x * 8 + rt) * 16;
    const float* xr = x + (r0 + m) * D_SZ + kg * 8;
    f16x8 bf[4];
#pragma unroll
    for (int kb = 0; kb < 4; ++kb) {
      float4 u0 = *(const float4*)(xr + kb * 32);
      float4 u1 = *(const float4*)(xr + kb * 32 + 4);
      f16x8 a;
      a[0] = (f16)u0.x; a[1] = (f16)u0.y; a[2] = (f16)u0.z; a[3] = (f16)u0.w;
      a[4] = (f16)u1.x; a[5] = (f16)u1.y; a[6] = (f16)u1.z; a[7] = (f16)u1.w;
      bf[kb] = a;
    }
    f32x4 acc[8];
#pragma unroll
    for (int t = 0; t < 8; ++t) acc[t] = (f32x4){0.f, 0.f, 0.f, 0.f};
#pragma unroll
    for (int kb = 0; kb < 4; ++kb)
#pragma unroll
      for (int t = 0; t < 8; ++t)
        acc[t] = __builtin_amdgcn_mfma_f32_16x16x32_f16(af[t][kb], bf[kb], acc[t], 0, 0, 0);
#pragma unroll
    for (int t = 0; t < 8; ++t) {
      const int c0 = ht + t * 16 + kg * 4;
      float4 bb = *(const float4*)(bias + c0);
      float4 o;
      o.x = acc[t][0] + bb.x;
      o.y = acc[t][1] + bb.y;
      o.z = acc[t][2] + bb.z;
      o.w = acc[t][3] + bb.w;
      *(float4*)(out + (r0 + m) * H_SZ + c0) = o;
    }
  }
}

__device__ __forceinline__ float fast_tanh(float y) {
  float e = __expf(2.0f * y);
  return 1.0f - __fdividef(2.0f, e + 1.0f);
}

__device__ __forceinline__ ull ld_agent(const ull* p) {
  return __hip_atomic_load(p, __ATOMIC_RELAXED, __HIP_MEMORY_SCOPE_AGENT);
}

// ---------------- recurrence: round-8 structure + lgkm-only B2 ----------------
// 32 blocks x 512 threads (8 waves x 1 j-tile, VGPR ~84).
// Exchange indexing ALL IN ULL UNITS (round-12 deadlock was gc4 kept in f16
// units -> polled unwritten addresses -> infinite spin):
//   per (g,slice) buffer = 512 ull; row m = 32 ull; thread covers 1 ull.
//   publish: pidx = (g*NS+sl)*512 + m*32 + (w*4+kg)  [f16 col w*16+kg*4]
//   gather:  gmr=tid>>5 (row), gcu=tid&31 (ull-in-row), f16 col = gcu*4.
__global__ __launch_bounds__(512) void ltc_rec_mfma(
    float* __restrict__ seq,        // [B][T][H]  in: x_in, out: h_seq
    float* __restrict__ h_last,     // [B][H]
    const float* __restrict__ hin,  // [B][H]
    const float* __restrict__ tau,  // [B]
    const float* __restrict__ Wrec, // [H][H] row-major
    ull* __restrict__ exu)          // [2][NG][NS][GB][SN] f16 ring, as ull
{
  __shared__ __attribute__((aligned(16))) f16 hs[2][GB * H_SZ];  // 2x16KB

  const int tid = threadIdx.x;
  const int g = blockIdx.x & 7;
  const int slice = blockIdx.x >> 3;
  const int w = tid >> 6;
  const int l = tid & 63;
  const int m = l & 15;
  const int kg = l >> 4;
  const int jt = slice * SN + w * 16;
  const int j0 = jt + kg * 4;
  const int b = g * GB + m;
  const int msk = (m & 7) << 3;

  // A-fragments, pre-rotated: afrag[0..3] = own-slice K, [4..15] = peer K.
  f16x8 afrag[16];
  {
    const float* wr = Wrec + (size_t)(jt + m) * H_SZ;
#pragma unroll
    for (int ff = 0; ff < 16; ++ff) {
      const int f = (slice * 4 + ff) & 15;
      const int k0 = f * 32 + kg * 8;
      float4 u0 = *(const float4*)(wr + k0);
      float4 u1 = *(const float4*)(wr + k0 + 4);
      f16x8 a;
      a[0] = (f16)u0.x; a[1] = (f16)u0.y; a[2] = (f16)u0.z; a[3] = (f16)u0.w;
      a[4] = (f16)u1.x; a[5] = (f16)u1.y; a[6] = (f16)u1.z; a[7] = (f16)u1.w;
      afrag[ff] = a;
    }
  }

  float hreg[4];
  {
    float4 h0 = *(const float4*)(hin + (size_t)b * H_SZ + j0);
    hreg[0] = h0.x; hreg[1] = h0.y; hreg[2] = h0.z; hreg[3] = h0.w;
  }
  const float itau = 1.0f / tau[b];

  // init: full h_0 into hs[0]
  {
    const int mr = tid >> 5;
    const int c4 = (tid & 31) * 4;
#pragma unroll
    for (int p = 0; p < 4; ++p) {
      const int col = p * SN + c4;
      float4 v = *(const float4*)(hin + (size_t)(g * GB + mr) * H_SZ + col);
      const int e = (mr * H_SZ + col) ^ ((mr & 7) << 3);
      f16x4 hf;
      hf[0] = (f16)v.x; hf[1] = (f16)v.y; hf[2] = (f16)v.z; hf[3] = (f16)v.w;
      *(f16x4*)&hs[0][e] = hf;
    }
  }
  __syncthreads();

  // ---- exchange addressing, ull units ----
  const uint pidx = (uint)((g * NS + slice) * 512 + m * 32 + w * 4 + kg);

  const int gmr = tid >> 5;      // gather row 0..15
  const int gcu = tid & 31;      // ull-in-row 0..31 (f16 col = gcu*4)
  const int psa = (slice + 1) & 3, psb = (slice + 2) & 3, psc = (slice + 3) & 3;
  const uint ga = (uint)((g * NS + psa) * 512 + gmr * 32 + gcu);
  const uint gb = (uint)((g * NS + psb) * 512 + gmr * 32 + gcu);
  const uint gc = (uint)((g * NS + psc) * 512 + gmr * 32 + gcu);
  const int ea = (gmr * H_SZ + psa * SN + gcu * 4) ^ ((gmr & 7) << 3);
  const int eb = (gmr * H_SZ + psb * SN + gcu * 4) ^ ((gmr & 7) << 3);
  const int ec = (gmr * H_SZ + psc * SN + gcu * 4) ^ ((gmr & 7) << 3);
  const int eown = (m * H_SZ + j0) ^ msk;

  // LDS byte offsets for the 16 k-block reads (literal ff indices)
  int ebase[16];
#pragma unroll
  for (int ff = 0; ff < 16; ++ff) {
    const int f = (slice * 4 + ff) & 15;
    ebase[ff] = (m * H_SZ + f * 32 + kg * 8) ^ msk;
  }

  float* seqp = seq + (size_t)b * T_SZ * H_SZ + j0;
  float4 xin = *(const float4*)seqp;

  for (int s = 0; s < T_SZ; ++s) {
    const int cur = s & 1, nxt = cur ^ 1;

    // ---- issue gather loads for h_s peer slices (pub'd end of iter s-1) ----
    ull w0 = 0, w1 = 0, w2 = 0;
    const uint voff = ((s - 1) & 1) ? (uint)RING_ULL : 0u;
    const ull ptag = (ull)(((s - 1) >> 1) & 1);
    if (s > 0) {
      w0 = ld_agent(exu + voff + ga);
      w1 = ld_agent(exu + voff + gb);
      w2 = ld_agent(exu + voff + gc);
    }

    // ---- own-K MFMA (afrag[0..3]): covers gather flight + prior publish ack ----
    f32x4 accA = {0.f, 0.f, 0.f, 0.f};
    accA = __builtin_amdgcn_mfma_f32_16x16x32_f16(afrag[0], *(const f16x8*)&hs[cur][ebase[0]], accA, 0, 0, 0);
    accA = __builtin_amdgcn_mfma_f32_16x16x32_f16(afrag[1], *(const f16x8*)&hs[cur][ebase[1]], accA, 0, 0, 0);
    accA = __builtin_amdgcn_mfma_f32_16x16x32_f16(afrag[2], *(const f16x8*)&hs[cur][ebase[2]], accA, 0, 0, 0);
    accA = __builtin_amdgcn_mfma_f32_16x16x32_f16(afrag[3], *(const f16x8*)&hs[cur][ebase[3]], accA, 0, 0, 0);

    if (s > 0) {
      // ---- poll tags; reload only stale words ----
      while ((w0 & 1ULL) != ptag) w0 = ld_agent(exu + voff + ga);
      while ((w1 & 1ULL) != ptag) w1 = ld_agent(exu + voff + gb);
      while ((w2 & 1ULL) != ptag) w2 = ld_agent(exu + voff + gc);
      // ---- peer slices of h_s into hs[cur] peer cols ----
      *(f16x4*)&hs[cur][ea] = __builtin_bit_cast(f16x4, w0);
      *(f16x4*)&hs[cur][eb] = __builtin_bit_cast(f16x4, w1);
      *(f16x4*)&hs[cur][ec] = __builtin_bit_cast(f16x4, w2);
      __syncthreads();  // B1: peer cols visible (vmcnt ~drained by poll)
    }

    // ---- peer-K MFMA (afrag[4..15], 2 chains) ----
    f32x4 accB = {0.f, 0.f, 0.f, 0.f};
    f32x4 accC = {0.f, 0.f, 0.f, 0.f};
    accB = __builtin_amdgcn_mfma_f32_16x16x32_f16(afrag[4],  *(const f16x8*)&hs[cur][ebase[4]],  accB, 0, 0, 0);
    accB = __builtin_amdgcn_mfma_f32_16x16x32_f16(afrag[5],  *(const f16x8*)&hs[cur][ebase[5]],  accB, 0, 0, 0);
    accB = __builtin_amdgcn_mfma_f32_16x16x32_f16(afrag[6],  *(const f16x8*)&hs[cur][ebase[6]],  accB, 0, 0, 0);
    accB = __builtin_amdgcn_mfma_f32_16x16x32_f16(afrag[7],  *(const f16x8*)&hs[cur][ebase[7]],  accB, 0, 0, 0);
    accB = __builtin_amdgcn_mfma_f32_16x16x32_f16(afrag[8],  *(const f16x8*)&hs[cur][ebase[8]],  accB, 0, 0, 0);
    accB = __builtin_amdgcn_mfma_f32_16x16x32_f16(afrag[9],  *(const f16x8*)&hs[cur][ebase[9]],  accB, 0, 0, 0);
    accC = __builtin_amdgcn_mfma_f32_16x16x32_f16(afrag[10], *(const f16x8*)&hs[cur][ebase[10]], accC, 0, 0, 0);
    accC = __builtin_amdgcn_mfma_f32_16x16x32_f16(afrag[11], *(const f16x8*)&hs[cur][ebase[11]], accC, 0, 0, 0);
    accC = __builtin_amdgcn_mfma_f32_16x16x32_f16(afrag[12], *(const f16x8*)&hs[cur][ebase[12]], accC, 0, 0, 0);
    accC = __builtin_amdgcn_mfma_f32_16x16x32_f16(afrag[13], *(const f16x8*)&hs[cur][ebase[13]], accC, 0, 0, 0);
    accC = __builtin_amdgcn_mfma_f32_16x16x32_f16(afrag[14], *(const f16x8*)&hs[cur][ebase[14]], accC, 0, 0, 0);
    accC = __builtin_amdgcn_mfma_f32_16x16x32_f16(afrag[15], *(const f16x8*)&hs[cur][ebase[15]], accC, 0, 0, 0);
    f32x4 acc = accA + accB + accC;

    // ---- epilogue ----
    float4 hv;
    hv.x = fmaf(fast_tanh(xin.x + acc[0]) - hreg[0], itau, hreg[0]);
    hv.y = fmaf(fast_tanh(xin.y + acc[1]) - hreg[1], itau, hreg[1]);
    hv.z = fmaf(fast_tanh(xin.z + acc[2]) - hreg[2], itau, hreg[2]);
    hv.w = fmaf(fast_tanh(xin.w + acc[3]) - hreg[3], itau, hreg[3]);
    hreg[0] = hv.x; hreg[1] = hv.y; hreg[2] = hv.z; hreg[3] = hv.w;

    f16x4 hf;
    hf[0] = (f16)hv.x; hf[1] = (f16)hv.y; hf[2] = (f16)hv.z; hf[3] = (f16)hv.w;

    // ---- publish h_{s+1}: slot s&1, tag (s>>1)&1 ----
    {
      ull bits = (__builtin_bit_cast(ull, hf) & ~1ULL) | (ull)((s >> 1) & 1);
      __hip_atomic_store(exu + (cur ? (uint)RING_ULL : 0u) + pidx, bits,
                         __ATOMIC_RELAXED, __HIP_MEMORY_SCOPE_AGENT);
    }

    // ---- local tail ----
    *(f16x4*)&hs[nxt][eown] = hf;   // own cols of h_{s+1}
    *(float4*)seqp = hv;            // h_seq output (plain cached)
    seqp += H_SZ;
    xin = *(const float4*)seqp;     // x_in prefetch for s+1

    BAR_LGKM();  // B2: LDS-only ordering; publish ack NOT drained here
  }

  float4 hv;
  hv.x = hreg[0]; hv.y = hreg[1]; hv.z = hreg[2]; hv.w = hreg[3];
  *(float4*)(h_last + (size_t)b * H_SZ + j0) = hv;
}

extern "C" void kernel_launch(void* const* d_in, const int* in_sizes, int n_in,
                              void* d_out, int out_size, void* d_ws, size_t ws_size,
                              hipStream_t stream) {
  const float* x     = (const float*)d_in[0];
  const float* hin   = (const float*)d_in[1];
  const float* tau   = (const float*)d_in[2];
  const float* Win_w = (const float*)d_in[3];
  const float* Win_b = (const float*)d_in[4];
  const float* Wrec  = (const float*)d_in[5];

  float* out    = (float*)d_out;
  float* seq    = out;
  float* h_last = out + (size_t)B_SZ * T_SZ * H_SZ;

  ull* ex = (ull*)d_ws;  // 256 KB (2-slot ring)

  // ring to 0xFF: LSB=1 never matches the first (tag-0) poll of each slot.
  hipMemsetAsync(ex, 0xFF, 2 * NG * NS * GB * SN * sizeof(f16), stream);

  input_proj_mfma<<<512, 256, 0, stream>>>(x, Win_w, Win_b, seq);
  ltc_rec_mfma<<<NG * NS, 512, 0, stream>>>(seq, h_last, hin, tau, Wrec, ex);
}

// Round 14
// 976.832 us; speedup vs baseline: 2.1194x; 1.0836x over previous
//
#include <hip/hip_runtime.h>

#define B_SZ 128
#define T_SZ 512
#define D_SZ 128
#define H_SZ 512

#define NG 8    // batch groups
#define GB 16   // batch rows per group
#define NS 4    // column slices
#define SN 128  // columns per slice

typedef _Float16 f16;
typedef _Float16 f16x8 __attribute__((ext_vector_type(8)));
typedef _Float16 f16x4 __attribute__((ext_vector_type(4)));
typedef float f32x4 __attribute__((ext_vector_type(4)));
typedef unsigned long long ull;
typedef unsigned int uint;

// ---------------- x_in = x @ W_in^T + b  (f16 MFMA, W in registers) --------
// Validated round 10: non-rec time 113 -> 54 us, absmax unchanged.
__global__ __launch_bounds__(256) void input_proj_mfma(
    const float* __restrict__ x,     // [BT][128]
    const float* __restrict__ Win,   // [512][128] row-major
    const float* __restrict__ bias,  // [512]
    float* __restrict__ out)         // [BT][512]
{
  const int tid = threadIdx.x;
  const int w = tid >> 6;
  const int l = tid & 63;
  const int m = l & 15;
  const int kg = l >> 4;
  const int ht = w * 128;

  f16x8 af[8][4];
#pragma unroll
  for (int t = 0; t < 8; ++t) {
    const float* wr = Win + (size_t)(ht + t * 16 + m) * D_SZ;
#pragma unroll
    for (int kb = 0; kb < 4; ++kb) {
      const int k0 = kb * 32 + kg * 8;
      float4 u0 = *(const float4*)(wr + k0);
      float4 u1 = *(const float4*)(wr + k0 + 4);
      f16x8 a;
      a[0] = (f16)u0.x; a[1] = (f16)u0.y; a[2] = (f16)u0.z; a[3] = (f16)u0.w;
      a[4] = (f16)u1.x; a[5] = (f16)u1.y; a[6] = (f16)u1.z; a[7] = (f16)u1.w;
      af[t][kb] = a;
    }
  }

  for (int rt = 0; rt < 8; ++rt) {
    const size_t r0 = ((size_t)blockIdx.x * 8 + rt) * 16;
    const float* xr = x + (r0 + m) * D_SZ + kg * 8;
    f16x8 bf[4];
#pragma unroll
    for (int kb = 0; kb < 4; ++kb) {
      float4 u0 = *(const float4*)(xr + kb * 32);
      float4 u1 = *(const float4*)(xr + kb * 32 + 4);
      f16x8 a;
      a[0] = (f16)u0.x; a[1] = (f16)u0.y; a[2] = (f16)u0.z; a[3] = (f16)u0.w;
      a[4] = (f16)u1.x; a[5] = (f16)u1.y; a[6] = (f16)u1.z; a[7] = (f16)u1.w;
      bf[kb] = a;
    }
    f32x4 acc[8];
#pragma unroll
    for (int t = 0; t < 8; ++t) acc[t] = (f32x4){0.f, 0.f, 0.f, 0.f};
#pragma unroll
    for (int kb = 0; kb < 4; ++kb)
#pragma unroll
      for (int t = 0; t < 8; ++t)
        acc[t] = __builtin_amdgcn_mfma_f32_16x16x32_f16(af[t][kb], bf[kb], acc[t], 0, 0, 0);
#pragma unroll
    for (int t = 0; t < 8; ++t) {
      const int c0 = ht + t * 16 + kg * 4;
      float4 bb = *(const float4*)(bias + c0);
      float4 o;
      o.x = acc[t][0] + bb.x;
      o.y = acc[t][1] + bb.y;
      o.z = acc[t][2] + bb.z;
      o.w = acc[t][3] + bb.w;
      *(float4*)(out + (r0 + m) * H_SZ + c0) = o;
    }
  }
}

__device__ __forceinline__ float fast_tanh(float y) {
  float e = __expf(2.0f * y);
  return 1.0f - __fdividef(2.0f, e + 1.0f);
}

__device__ __forceinline__ ull ld_agent(const ull* p) {
  return __hip_atomic_load(p, __ATOMIC_RELAXED, __HIP_MEMORY_SCOPE_AGENT);
}

// ---------------- recurrence: ROUND-8 VERBATIM (917 us, VGPR 84) ----------
// 32 blocks x 512 threads (8 waves). Exchange via SELF-TAGGED 8B payloads
// (LSB of f16[0] = generation parity) on a depth-2 LLC ring (relaxed sc1).
// Pipeline per iter: issue gathers -> own-K MFMA (no peer dep, covers the
// LLC RTT) -> poll tags -> peer cols into hs[cur] -> B1 -> peer-K MFMA
// -> epilogue -> tagged publish -> own cols into hs[nxt] -> B2.
// B2 = __syncthreads (vmcnt drain): acts as PACING — keeps the 4 peer
// blocks loosely lockstepped so top-of-iter gathers hit first try
// (round 13 falsified the lgkm-only variant: +88us, +4MB retries).
// afrag pre-rotated: in-loop indices literal (rule 20: runtime-indexed
// ext_vector arrays spill to scratch — round 7's 2.4x regression).
__global__ __launch_bounds__(512) void ltc_rec_mfma(
    float* __restrict__ seq,        // [B][T][H]  in: x_in, out: h_seq
    float* __restrict__ h_last,     // [B][H]
    const float* __restrict__ hin,  // [B][H]
    const float* __restrict__ tau,  // [B]
    const float* __restrict__ Wrec, // [H][H] row-major
    f16* __restrict__ ex)           // [2][NG][NS][GB][SN] exchange ring
{
  __shared__ f16 hs[2][GB * H_SZ];  // double-buffered, XOR-swizzled, 2x16KB

  const int tid = threadIdx.x;
  const int g = blockIdx.x & 7;
  const int slice = blockIdx.x >> 3;
  const int w = tid >> 6;          // wave 0..7
  const int l = tid & 63;
  const int m = l & 15;            // batch-in-group (MFMA col)
  const int kg = l >> 4;           // 0..3
  const int jt = slice * SN + w * 16;
  const int j0 = jt + kg * 4;
  const int b = g * GB + m;

  // one-time: A-fragments, pre-rotated so in-loop indices are literals.
  f16x8 afrag[16];
  {
    const float* wr = Wrec + (size_t)(jt + m) * H_SZ;
#pragma unroll
    for (int ff = 0; ff < 16; ++ff) {
      const int f = (slice * 4 + ff) & 15;   // runtime k-block, load-addr only
      const int k0 = f * 32 + kg * 8;
      float4 u0 = *(const float4*)(wr + k0);
      float4 u1 = *(const float4*)(wr + k0 + 4);
      f16x8 a;
      a[0] = (f16)u0.x; a[1] = (f16)u0.y; a[2] = (f16)u0.z; a[3] = (f16)u0.w;
      a[4] = (f16)u1.x; a[5] = (f16)u1.y; a[6] = (f16)u1.z; a[7] = (f16)u1.w;
      afrag[ff] = a;                          // compile-time index
    }
  }

  float hreg[4];
  {
    float4 h0 = *(const float4*)(hin + (size_t)b * H_SZ + j0);
    hreg[0] = h0.x; hreg[1] = h0.y; hreg[2] = h0.z; hreg[3] = h0.w;
  }
  const float itau = 1.0f / tau[b];

  // init: full h_0 into hs[0] as f16
  {
    const int mr = tid >> 5;         // 0..15
    const int c4 = (tid & 31) * 4;
#pragma unroll
    for (int p = 0; p < 4; ++p) {
      const int col = p * SN + c4;
      float4 v = *(const float4*)(hin + (size_t)(g * GB + mr) * H_SZ + col);
      const int e = (mr * H_SZ + col) ^ ((mr & 7) << 3);
      f16x4 hf;
      hf[0] = (f16)v.x; hf[1] = (f16)v.y; hf[2] = (f16)v.z; hf[3] = (f16)v.w;
      *(f16x4*)&hs[0][e] = hf;
    }
  }
  __syncthreads();

  // exchange addressing (ull units)
  const size_t EXB = (size_t)GB * SN;                 // 2048 f16
  const size_t RING_ULL = (size_t)NG * NS * EXB / 4;  // 16384 ull per slot
  ull* pub0 = (ull*)(ex + ((size_t)g * NS + slice) * EXB + (size_t)m * SN + (w * 16 + kg * 4));

  const int gmr = tid >> 5;
  const int gc4 = (tid & 31) * 4;
  const int psa = (slice + 1) & 3, psb = (slice + 2) & 3, psc = (slice + 3) & 3;
  const ull* ga0 = (const ull*)(ex + ((size_t)g * NS + psa) * EXB + (size_t)gmr * SN + gc4);
  const ull* gb0 = (const ull*)(ex + ((size_t)g * NS + psb) * EXB + (size_t)gmr * SN + gc4);
  const ull* gc0 = (const ull*)(ex + ((size_t)g * NS + psc) * EXB + (size_t)gmr * SN + gc4);
  const int ea = (gmr * H_SZ + psa * SN + gc4) ^ ((gmr & 7) << 3);
  const int eb = (gmr * H_SZ + psb * SN + gc4) ^ ((gmr & 7) << 3);
  const int ec = (gmr * H_SZ + psc * SN + gc4) ^ ((gmr & 7) << 3);
  const int eown = (m * H_SZ + j0) ^ ((m & 7) << 3);

  // base byte-offsets for the k-block LDS reads (runtime f folded into
  // address arithmetic; array indices below stay literal)
  int ebase[16];
#pragma unroll
  for (int ff = 0; ff < 16; ++ff) {
    const int f = (slice * 4 + ff) & 15;
    ebase[ff] = (m * H_SZ + f * 32 + kg * 8) ^ ((m & 7) << 3);
  }

  float* seqp = seq + (size_t)b * T_SZ * H_SZ + j0;
  float4 xin = *(const float4*)seqp;  // step-0 x_in prefetch

  for (int s = 0; s < T_SZ; ++s) {
    const int cur = s & 1, nxt = cur ^ 1;

    // ---- issue gather loads for h_s peer slices (pub'd end of iter s-1) ----
    ull w0 = 0, w1 = 0, w2 = 0;
    const size_t proff = nxt ? RING_ULL : 0;          // slot (s-1)&1
    const ull ptag = (ull)(((s - 1) >> 1) & 1);
    if (s > 0) {
      w0 = ld_agent(ga0 + proff);
      w1 = ld_agent(gb0 + proff);
      w2 = ld_agent(gc0 + proff);
    }

    // ---- own-K MFMA (afrag[0..3], no peer dep): covers the gather RTT ----
    f32x4 accA = {0.f, 0.f, 0.f, 0.f};
    accA = __builtin_amdgcn_mfma_f32_16x16x32_f16(afrag[0], *(const f16x8*)&hs[cur][ebase[0]], accA, 0, 0, 0);
    accA = __builtin_amdgcn_mfma_f32_16x16x32_f16(afrag[1], *(const f16x8*)&hs[cur][ebase[1]], accA, 0, 0, 0);
    accA = __builtin_amdgcn_mfma_f32_16x16x32_f16(afrag[2], *(const f16x8*)&hs[cur][ebase[2]], accA, 0, 0, 0);
    accA = __builtin_amdgcn_mfma_f32_16x16x32_f16(afrag[3], *(const f16x8*)&hs[cur][ebase[3]], accA, 0, 0, 0);

    if (s > 0) {
      // ---- poll tags; reload only stale words ----
      while ((w0 & 1ULL) != ptag) w0 = ld_agent(ga0 + proff);
      while ((w1 & 1ULL) != ptag) w1 = ld_agent(gb0 + proff);
      while ((w2 & 1ULL) != ptag) w2 = ld_agent(gc0 + proff);
      // ---- peer slices of h_s into hs[cur] peer cols ----
      *(f16x4*)&hs[cur][ea] = __builtin_bit_cast(f16x4, w0);
      *(f16x4*)&hs[cur][eb] = __builtin_bit_cast(f16x4, w1);
      *(f16x4*)&hs[cur][ec] = __builtin_bit_cast(f16x4, w2);
      __syncthreads();  // B1: peer cols visible block-wide
    }

    // ---- peer-K MFMA (afrag[4..15], 2 chains) ----
    f32x4 accB = {0.f, 0.f, 0.f, 0.f};
    f32x4 accC = {0.f, 0.f, 0.f, 0.f};
    accB = __builtin_amdgcn_mfma_f32_16x16x32_f16(afrag[4],  *(const f16x8*)&hs[cur][ebase[4]],  accB, 0, 0, 0);
    accB = __builtin_amdgcn_mfma_f32_16x16x32_f16(afrag[5],  *(const f16x8*)&hs[cur][ebase[5]],  accB, 0, 0, 0);
    accB = __builtin_amdgcn_mfma_f32_16x16x32_f16(afrag[6],  *(const f16x8*)&hs[cur][ebase[6]],  accB, 0, 0, 0);
    accB = __builtin_amdgcn_mfma_f32_16x16x32_f16(afrag[7],  *(const f16x8*)&hs[cur][ebase[7]],  accB, 0, 0, 0);
    accB = __builtin_amdgcn_mfma_f32_16x16x32_f16(afrag[8],  *(const f16x8*)&hs[cur][ebase[8]],  accB, 0, 0, 0);
    accB = __builtin_amdgcn_mfma_f32_16x16x32_f16(afrag[9],  *(const f16x8*)&hs[cur][ebase[9]],  accB, 0, 0, 0);
    accC = __builtin_amdgcn_mfma_f32_16x16x32_f16(afrag[10], *(const f16x8*)&hs[cur][ebase[10]], accC, 0, 0, 0);
    accC = __builtin_amdgcn_mfma_f32_16x16x32_f16(afrag[11], *(const f16x8*)&hs[cur][ebase[11]], accC, 0, 0, 0);
    accC = __builtin_amdgcn_mfma_f32_16x16x32_f16(afrag[12], *(const f16x8*)&hs[cur][ebase[12]], accC, 0, 0, 0);
    accC = __builtin_amdgcn_mfma_f32_16x16x32_f16(afrag[13], *(const f16x8*)&hs[cur][ebase[13]], accC, 0, 0, 0);
    accC = __builtin_amdgcn_mfma_f32_16x16x32_f16(afrag[14], *(const f16x8*)&hs[cur][ebase[14]], accC, 0, 0, 0);
    accC = __builtin_amdgcn_mfma_f32_16x16x32_f16(afrag[15], *(const f16x8*)&hs[cur][ebase[15]], accC, 0, 0, 0);
    f32x4 acc = accA + accB + accC;

    // ---- epilogue ----
    float4 hv;
    hv.x = fmaf(fast_tanh(xin.x + acc[0]) - hreg[0], itau, hreg[0]);
    hv.y = fmaf(fast_tanh(xin.y + acc[1]) - hreg[1], itau, hreg[1]);
    hv.z = fmaf(fast_tanh(xin.z + acc[2]) - hreg[2], itau, hreg[2]);
    hv.w = fmaf(fast_tanh(xin.w + acc[3]) - hreg[3], itau, hreg[3]);
    hreg[0] = hv.x; hreg[1] = hv.y; hreg[2] = hv.z; hreg[3] = hv.w;

    f16x4 hf;
    hf[0] = (f16)hv.x; hf[1] = (f16)hv.y; hf[2] = (f16)hv.z; hf[3] = (f16)hv.w;

    // ---- publish h_{s+1} FIRST: tagged word, slot s&1, tag (s>>1)&1 ----
    {
      ull bits = __builtin_bit_cast(ull, hf);
      bits = (bits & ~1ULL) | (ull)((s >> 1) & 1);
      __hip_atomic_store(pub0 + (cur ? RING_ULL : 0), bits,
                         __ATOMIC_RELAXED, __HIP_MEMORY_SCOPE_AGENT);
    }

    // ---- local tail ----
    *(f16x4*)&hs[nxt][eown] = hf;       // own slice of h_{s+1} (exact f16)
    *(float4*)seqp = hv;                // h_seq output (plain cached)
    seqp += H_SZ;
    xin = *(const float4*)seqp;         // x_in prefetch for s+1

    __syncthreads();  // B2: own cols ready + vmcnt drain (peer pacing)
  }

  float4 hv;
  hv.x = hreg[0]; hv.y = hreg[1]; hv.z = hreg[2]; hv.w = hreg[3];
  *(float4*)(h_last + (size_t)b * H_SZ + j0) = hv;
}

extern "C" void kernel_launch(void* const* d_in, const int* in_sizes, int n_in,
                              void* d_out, int out_size, void* d_ws, size_t ws_size,
                              hipStream_t stream) {
  const float* x     = (const float*)d_in[0];
  const float* hin   = (const float*)d_in[1];
  const float* tau   = (const float*)d_in[2];
  const float* Win_w = (const float*)d_in[3];
  const float* Win_b = (const float*)d_in[4];
  const float* Wrec  = (const float*)d_in[5];

  float* out    = (float*)d_out;
  float* seq    = out;
  float* h_last = out + (size_t)B_SZ * T_SZ * H_SZ;

  f16* ex = (f16*)d_ws;  // 256 KB (2-slot ring)

  // ring to 0xFF: LSB=1 never matches the first (tag-0) poll of each slot.
  hipMemsetAsync(ex, 0xFF, 2 * NG * NS * GB * SN * sizeof(f16), stream);

  input_proj_mfma<<<512, 256, 0, stream>>>(x, Win_w, Win_b, seq);
  ltc_rec_mfma<<<NG * NS, 512, 0, stream>>>(seq, h_last, hin, tau, Wrec, ex);
}